// Round 4
// baseline (216.662 us; speedup 1.0000x reference)
//
#include <hip/hip_runtime.h>
#include <hip/hip_bf16.h>

#define B_ 4
#define N_ 16384
#define K_ 16
#define NEG 0.2f
#define EPSBN 1e-5f
#define INV_SIG2 2500.0f

typedef unsigned short u16;
typedef unsigned int   u32;
typedef __attribute__((ext_vector_type(8))) short short8;
typedef __attribute__((ext_vector_type(4))) float f32x4;

__device__ __forceinline__ float bf2f(u16 h){
  return __uint_as_float(((u32)h) << 16);
}
__device__ __forceinline__ u16 f2bf(float f){
  u32 x = __float_as_uint(f);
  x += 0x7fffu + ((x >> 16) & 1u);
  return (u16)(x >> 16);
}
__device__ __forceinline__ int comp4(int4 r, int c){
  return c == 0 ? r.x : (c == 1 ? r.y : (c == 2 ? r.z : r.w));
}

// ---------------- K0: wconv [o][c][j] fp32 -> wbf [j][o][c] bf16 ----------------
__global__ void k0_wprep(const float* __restrict__ wconv, u16* __restrict__ wbf){
  const int idx = blockIdx.x * 256 + threadIdx.x;
  if (idx < 9*128*64){
    const int j = idx >> 13;
    const int rem = idx & 8191;
    const int o = rem >> 6, c = rem & 63;
    wbf[idx] = f2bf(wconv[(o*64 + c)*9 + j]);
  }
}

// ---------------- K1: u = (W1-W2)^T x, v = W2^T x, stored [B][N][64] bf16 --------
__global__ __launch_bounds__(256) void k1_uv(const float* __restrict__ x,
                                             const float* __restrict__ we,
                                             u16* __restrict__ uo,
                                             u16* __restrict__ vo){
  const int n0 = blockIdx.x * 128;
  const int b  = blockIdx.y;
  __shared__ u16   Wl[64*128];   // [c'][r] bf16, r<64 -> WA=W1-W2, r>=64 -> WB=W2
  __shared__ float Xl[64*128];   // [c'][n]
  const int tid = threadIdx.x;
  for (int idx = tid; idx < 64*128; idx += 256){
    const int cp = idx >> 7, r = idx & 127;
    float w;
    if (r < 64) w = we[r*128 + cp] - we[r*128 + 64 + cp];
    else        w = we[(r-64)*128 + 64 + cp];
    Wl[cp*128 + r] = f2bf(w);
  }
  for (int idx = tid; idx < 64*128; idx += 256){
    const int cp = idx >> 7, nl = idx & 127;
    Xl[cp*128 + nl] = x[(b*64 + cp)*N_ + n0 + nl];
  }
  __syncthreads();
  const int tr = tid & 15, tc = tid >> 4;
  float acc[8][8];
  #pragma unroll
  for (int i=0;i<8;++i)
    #pragma unroll
    for (int j=0;j<8;++j) acc[i][j] = 0.f;
  for (int cp=0; cp<64; ++cp){
    const uint4 wv = *(const uint4*)&Wl[cp*128 + tr*8];
    float wr[8];
    wr[0]=__uint_as_float(wv.x<<16); wr[1]=__uint_as_float(wv.x & 0xffff0000u);
    wr[2]=__uint_as_float(wv.y<<16); wr[3]=__uint_as_float(wv.y & 0xffff0000u);
    wr[4]=__uint_as_float(wv.z<<16); wr[5]=__uint_as_float(wv.z & 0xffff0000u);
    wr[6]=__uint_as_float(wv.w<<16); wr[7]=__uint_as_float(wv.w & 0xffff0000u);
    const float4 x0 = *(const float4*)&Xl[cp*128 + tc*8];
    const float4 x1 = *(const float4*)&Xl[cp*128 + tc*8 + 4];
    const float xr[8] = {x0.x,x0.y,x0.z,x0.w,x1.x,x1.y,x1.z,x1.w};
    #pragma unroll
    for (int i=0;i<8;++i)
      #pragma unroll
      for (int j=0;j<8;++j)
        acc[i][j] = fmaf(wr[i], xr[j], acc[i][j]);
  }
  u16* dst = (tr < 8) ? uo : vo;
  const int cb = (tr & 7) * 8;
  #pragma unroll
  for (int ni=0; ni<8; ++ni){
    const int n = n0 + tc*8 + ni;
    u32 p0 = (u32)f2bf(acc[0][ni]) | ((u32)f2bf(acc[1][ni]) << 16);
    u32 p1 = (u32)f2bf(acc[2][ni]) | ((u32)f2bf(acc[3][ni]) << 16);
    u32 p2 = (u32)f2bf(acc[4][ni]) | ((u32)f2bf(acc[5][ni]) << 16);
    u32 p3 = (u32)f2bf(acc[6][ni]) | ((u32)f2bf(acc[7][ni]) << 16);
    *(uint4*)&dst[(b*N_ + n)*64 + cb] = make_uint4(p0,p1,p2,p3);
  }
}

// ---------------- K2 v3: gather h = u[i]+v[j]; per-(b,n) max/min; stats ----------
// 2048 blocks x 256 thr, XCD-pinned batch (b = (bid&7)>>1). lane = channel.
// eidx for the wave's 8 points prefetched once (int4/lane); per point-pair 64
// independent 2B gather loads in flight (load/combine split).
__global__ __launch_bounds__(256) void k2_gather(const u16* __restrict__ uo,
                                                 const u16* __restrict__ vo,
                                                 const int* __restrict__ eidx,
                                                 u16* __restrict__ wmaxo,
                                                 u16* __restrict__ wmino,
                                                 float* __restrict__ stats){
  const int bid = blockIdx.x;
  const int xcd = bid & 7;
  const int b   = xcd >> 1;
  const int n0  = ((bid >> 3) + (xcd & 1)*256) * 32;
  const int tid = threadIdx.x;
  const int wid = tid >> 6, lane = tid & 63;
  const int nb  = n0 + wid*8;          // wave's 8 points
  const u16* ub = uo + (size_t)b*N_*64 + lane;
  const u16* vb = vo + (size_t)b*N_*64 + lane;

  // prefetch edge indices: lanes 0..31 hold eidx[0][b][nb..nb+7][*] (128 ints),
  // lanes 32..63 hold eidx[1][...] (128 ints); int4 per lane.
  const int* e0 = eidx + (b*N_ + nb)*K_;
  const int* e1 = eidx + B_*N_*K_ + (b*N_ + nb)*K_;
  const int4 r = (lane < 32) ? *(const int4*)(e0 + lane*4)
                             : *(const int4*)(e1 + (lane - 32)*4);

  float ssum = 0.f, ssq = 0.f;
  __shared__ float redS[4][64], redQ[4][64];

  for (int ip = 0; ip < 4; ++ip){
    float h[2][16];
    #pragma unroll
    for (int p = 0; p < 2; ++p){
      #pragma unroll
      for (int k = 0; k < 16; ++k){
        const int flat = (ip*2 + p)*16 + k;     // flat&3 == k&3 (static)
        const int src  = flat >> 2;
        const int jj = __shfl(comp4(r, k & 3), src);
        const int ii = __shfl(comp4(r, k & 3), 32 + src);
        h[p][k] = bf2f(ub[(size_t)ii*64]) + bf2f(vb[(size_t)jj*64]);
      }
    }
    #pragma unroll
    for (int p = 0; p < 2; ++p){
      float mx = h[p][0], mn = h[p][0];
      float s0 = h[p][0];
      float q0 = h[p][0]*h[p][0];
      #pragma unroll
      for (int k = 1; k < 16; ++k){
        mx = fmaxf(mx, h[p][k]);
        mn = fminf(mn, h[p][k]);
        s0 += h[p][k];
        q0 = fmaf(h[p][k], h[p][k], q0);
      }
      ssum += s0;
      ssq  += q0;
      const int n = nb + ip*2 + p;
      wmaxo[((size_t)(b*N_ + n))*64 + lane] = f2bf(mx);
      wmino[((size_t)(b*N_ + n))*64 + lane] = f2bf(mn);
    }
  }

  redS[wid][lane] = ssum;
  redQ[wid][lane] = ssq;
  __syncthreads();
  if (tid < 64){
    atomicAdd(&stats[tid], redS[0][tid] + redS[1][tid] + redS[2][tid] + redS[3][tid]);
  } else if (tid < 128){
    const int c = tid - 64;
    atomicAdd(&stats[64 + c], redQ[0][c] + redQ[1][c] + redQ[2][c] + redQ[3][c]);
  }
}

// ---------------- K3: finalize BN affine: sct[c]=scale, sct[64+c]=shift ----------
__global__ void k3_finalize(const float* __restrict__ stats,
                            const float* __restrict__ gamma,
                            const float* __restrict__ beta,
                            float* __restrict__ sct){
  const int c = threadIdx.x;
  const float inv = 1.0f / (float)(B_*N_*K_);
  const float mean = stats[c] * inv;
  const float var  = stats[64+c] * inv - mean*mean;
  const float s = gamma[c] * rsqrtf(var + EPSBN);
  sct[c] = s;
  sct[64+c] = beta[c] - mean*s;
}

// ---------------- K4: MFMA weighted conv ------------------------------------------
// grid (N/64, B), block 256 (4 waves). Wave w: o in [w*32, w*32+32), n-tile 64.
// out[o][n] = sum_j wgt[j][n] * (Wj x hbn_shift_j)[o][n] + bias
__global__ __launch_bounds__(256) void k4_mfma(const u16* __restrict__ wmaxo,
                                               const u16* __restrict__ wmino,
                                               const float* __restrict__ sct,
                                               const float* __restrict__ coords,
                                               const u16* __restrict__ wbf,
                                               const float* __restrict__ bconv,
                                               float* __restrict__ out){
  const int n0 = blockIdx.x * 64;
  const int b  = blockIdx.y;
  const int tid = threadIdx.x;
  const int w = tid >> 6, lane = tid & 63;
  const int r15 = lane & 15, kg = lane >> 4;

  __shared__ u16 hl[72*72];     // [m_local][c], row stride 72 (pad) -> 10.4 KB
  __shared__ float wgt[9*64];   // [j][n] Gaussian weights

  // --- build hbn tile: h = leaky(s*max_or_min + t), rows m = n0-4 .. n0+67
  {
    const int c = tid & 63;
    const float s = sct[c], t = sct[64+c];
    const u16* src = ((s >= 0.f) ? wmaxo : wmino) + (size_t)b*N_*64 + c;
    #pragma unroll
    for (int it = 0; it < 18; ++it){
      const int ml = (tid >> 6) + it*4;
      const int m = n0 - 4 + ml;
      float hv = 0.f;
      if (m >= 0 && m < N_){
        hv = fmaf(s, bf2f(src[(size_t)m*64]), t);
        hv = (hv >= 0.f) ? hv : NEG*hv;
      }
      hl[ml*72 + c] = f2bf(hv);
    }
  }
  // --- build Gaussian weights wgt[j][n]
  for (int idx = tid; idx < 576; idx += 256){
    const int j = idx >> 6, n = idx & 63;
    const int mc = n0 + n, mt = mc + j - 4;
    float wv = 0.f;
    if (mt >= 0 && mt < N_){
      float d2 = 0.f;
      #pragma unroll
      for (int d = 0; d < 3; ++d){
        const float dd = coords[(b*3+d)*N_ + mt] - coords[(b*3+d)*N_ + mc];
        d2 = fmaf(dd, dd, d2);
      }
      wv = __expf(-INV_SIG2 * d2);
    }
    wgt[idx] = wv;
  }
  __syncthreads();

  // --- MFMA main loop over taps j
  const u16* abase = wbf + ((w*32 + r15)*64 + kg*8);   // + j*8192 + of*1024 + cc
  const u16* hbase = &hl[r15*72 + kg*8];               // + (nf*16 + j)*72 + cc
  f32x4 acc[2][4] = {};
  const f32x4 zero = {0.f, 0.f, 0.f, 0.f};

  for (int j = 0; j < 9; ++j){
    float wj[4];
    #pragma unroll
    for (int nf = 0; nf < 4; ++nf) wj[nf] = wgt[j*64 + nf*16 + r15];
    short8 bfr[4][2];
    #pragma unroll
    for (int nf = 0; nf < 4; ++nf){
      bfr[nf][0] = *(const short8*)&hbase[(nf*16 + j)*72];
      bfr[nf][1] = *(const short8*)&hbase[(nf*16 + j)*72 + 32];
    }
    #pragma unroll
    for (int of = 0; of < 2; ++of){
      const short8 a0 = *(const short8*)&abase[j*8192 + of*1024];
      const short8 a1 = *(const short8*)&abase[j*8192 + of*1024 + 32];
      #pragma unroll
      for (int nf = 0; nf < 4; ++nf){
        f32x4 p = __builtin_amdgcn_mfma_f32_16x16x32_bf16(a0, bfr[nf][0], zero, 0, 0, 0);
        p = __builtin_amdgcn_mfma_f32_16x16x32_bf16(a1, bfr[nf][1], p, 0, 0, 0);
        #pragma unroll
        for (int r = 0; r < 4; ++r)
          acc[of][nf][r] = fmaf(wj[nf], p[r], acc[of][nf][r]);
      }
    }
  }

  // --- epilogue: D layout col = lane&15, row = (lane>>4)*4 + reg
  #pragma unroll
  for (int of = 0; of < 2; ++of){
    #pragma unroll
    for (int r = 0; r < 4; ++r){
      const int o = w*32 + of*16 + kg*4 + r;
      const float bs = bconv[o];
      float* dst = &out[(size_t)(b*128 + o)*N_ + n0 + r15];
      #pragma unroll
      for (int nf = 0; nf < 4; ++nf)
        dst[nf*16] = acc[of][nf][r] + bs;
    }
  }
}

extern "C" void kernel_launch(void* const* d_in, const int* in_sizes, int n_in,
                              void* d_out, int out_size, void* d_ws, size_t ws_size,
                              hipStream_t stream){
  const float* x      = (const float*)d_in[0];
  const float* coords = (const float*)d_in[1];
  const int*   eidx   = (const int*)  d_in[2];
  const float* we     = (const float*)d_in[3];
  const float* gamma  = (const float*)d_in[4];
  const float* beta   = (const float*)d_in[5];
  const float* wconv  = (const float*)d_in[6];
  const float* bconv  = (const float*)d_in[7];
  float* out = (float*)d_out;
  char* ws = (char*)d_ws;
  // ws layout (bytes): u[8.39MB] v[8.39MB] wmax[8.39MB] wmin[8.39MB] stats[512] sct[512] wbf[147KB]
  u16* u     = (u16*)(ws);
  u16* v     = (u16*)(ws + 8388608);
  u16* wmax_ = (u16*)(ws + 16777216);
  u16* wmin_ = (u16*)(ws + 25165824);
  float* stats = (float*)(ws + 33554432);
  float* sct   = (float*)(ws + 33554944);
  u16* wbf     = (u16*)(ws + 33555456);

  hipMemsetAsync(stats, 0, 512, stream);
  k0_wprep<<<288, 256, 0, stream>>>(wconv, wbf);
  k1_uv<<<dim3(N_/128, B_), 256, 0, stream>>>(x, we, u, v);
  k2_gather<<<2048, 256, 0, stream>>>(u, v, eidx, wmax_, wmin_, stats);
  k3_finalize<<<1, 64, 0, stream>>>(stats, gamma, beta, sct);
  k4_mfma<<<dim3(N_/64, B_), 256, 0, stream>>>(wmax_, wmin_, sct, coords, wbf, bconv, out);
}

// Round 5
// 152.188 us; speedup vs baseline: 1.4236x; 1.4236x over previous
//
#include <hip/hip_runtime.h>
#include <hip/hip_bf16.h>

#define B_ 4
#define N_ 16384
#define K_ 16
#define NEG 0.2f
#define EPSBN 1e-5f
#define INV_SIG2 2500.0f

typedef unsigned short u16;
typedef unsigned int   u32;
typedef __attribute__((ext_vector_type(8))) short short8;
typedef __attribute__((ext_vector_type(4))) float f32x4;

__device__ __forceinline__ float bf2f(u16 h){
  return __uint_as_float(((u32)h) << 16);
}
__device__ __forceinline__ u16 f2bf(float f){
  u32 x = __float_as_uint(f);
  x += 0x7fffu + ((x >> 16) & 1u);
  return (u16)(x >> 16);
}
__device__ __forceinline__ int comp4(int4 r, int c){
  return c == 0 ? r.x : (c == 1 ? r.y : (c == 2 ? r.z : r.w));
}

// ---------------- K0: wconv [o][c][j] fp32 -> wbf [j][o][c] bf16 ----------------
__global__ void k0_wprep(const float* __restrict__ wconv, u16* __restrict__ wbf){
  const int idx = blockIdx.x * 256 + threadIdx.x;
  if (idx < 9*128*64){
    const int j = idx >> 13;
    const int rem = idx & 8191;
    const int o = rem >> 6, c = rem & 63;
    wbf[idx] = f2bf(wconv[(o*64 + c)*9 + j]);
  }
}

// ---------------- K1: u = (W1-W2)^T x, v = W2^T x, stored [B][N][64] bf16 --------
__global__ __launch_bounds__(256) void k1_uv(const float* __restrict__ x,
                                             const float* __restrict__ we,
                                             u16* __restrict__ uo,
                                             u16* __restrict__ vo){
  const int n0 = blockIdx.x * 128;
  const int b  = blockIdx.y;
  __shared__ u16   Wl[64*128];   // [c'][r] bf16, r<64 -> WA=W1-W2, r>=64 -> WB=W2
  __shared__ float Xl[64*128];   // [c'][n]
  const int tid = threadIdx.x;
  for (int idx = tid; idx < 64*128; idx += 256){
    const int cp = idx >> 7, r = idx & 127;
    float w;
    if (r < 64) w = we[r*128 + cp] - we[r*128 + 64 + cp];
    else        w = we[(r-64)*128 + 64 + cp];
    Wl[cp*128 + r] = f2bf(w);
  }
  for (int idx = tid; idx < 64*128; idx += 256){
    const int cp = idx >> 7, nl = idx & 127;
    Xl[cp*128 + nl] = x[(b*64 + cp)*N_ + n0 + nl];
  }
  __syncthreads();
  const int tr = tid & 15, tc = tid >> 4;
  float acc[8][8];
  #pragma unroll
  for (int i=0;i<8;++i)
    #pragma unroll
    for (int j=0;j<8;++j) acc[i][j] = 0.f;
  for (int cp=0; cp<64; ++cp){
    const uint4 wv = *(const uint4*)&Wl[cp*128 + tr*8];
    float wr[8];
    wr[0]=__uint_as_float(wv.x<<16); wr[1]=__uint_as_float(wv.x & 0xffff0000u);
    wr[2]=__uint_as_float(wv.y<<16); wr[3]=__uint_as_float(wv.y & 0xffff0000u);
    wr[4]=__uint_as_float(wv.z<<16); wr[5]=__uint_as_float(wv.z & 0xffff0000u);
    wr[6]=__uint_as_float(wv.w<<16); wr[7]=__uint_as_float(wv.w & 0xffff0000u);
    const float4 x0 = *(const float4*)&Xl[cp*128 + tc*8];
    const float4 x1 = *(const float4*)&Xl[cp*128 + tc*8 + 4];
    const float xr[8] = {x0.x,x0.y,x0.z,x0.w,x1.x,x1.y,x1.z,x1.w};
    #pragma unroll
    for (int i=0;i<8;++i)
      #pragma unroll
      for (int j=0;j<8;++j)
        acc[i][j] = fmaf(wr[i], xr[j], acc[i][j]);
  }
  u16* dst = (tr < 8) ? uo : vo;
  const int cb = (tr & 7) * 8;
  #pragma unroll
  for (int ni=0; ni<8; ++ni){
    const int n = n0 + tc*8 + ni;
    u32 p0 = (u32)f2bf(acc[0][ni]) | ((u32)f2bf(acc[1][ni]) << 16);
    u32 p1 = (u32)f2bf(acc[2][ni]) | ((u32)f2bf(acc[3][ni]) << 16);
    u32 p2 = (u32)f2bf(acc[4][ni]) | ((u32)f2bf(acc[5][ni]) << 16);
    u32 p3 = (u32)f2bf(acc[6][ni]) | ((u32)f2bf(acc[7][ni]) << 16);
    *(uint4*)&dst[(b*N_ + n)*64 + cb] = make_uint4(p0,p1,p2,p3);
  }
}

// ---------------- K2 v4: gather h = u[i]+v[j]; per-(b,n) max/min; stats ----------
// Round-2 inner structure (lane = channel, coalesced 128B row gathers, tight
// consume-immediately chain, minimal VGPR) + 2048 blocks (8 pts/wave -> 8
// blocks/CU potential) + XCD-pinned batches + one up-front int4 eidx prefetch.
__global__ __launch_bounds__(256) void k2_gather(const u16* __restrict__ uo,
                                                 const u16* __restrict__ vo,
                                                 const int* __restrict__ eidx,
                                                 u16* __restrict__ wmaxo,
                                                 u16* __restrict__ wmino,
                                                 float* __restrict__ stats){
  const int bid = blockIdx.x;
  const int xcd = bid & 7;
  const int b   = xcd >> 1;
  const int n0  = ((bid >> 3) + (xcd & 1)*256) * 32;
  const int tid = threadIdx.x;
  const int wid = tid >> 6, lane = tid & 63;
  const int nb  = n0 + wid*8;          // wave's 8 points
  const u16* ub = uo + (size_t)b*N_*64;
  const u16* vb = vo + (size_t)b*N_*64;

  // prefetch edge indices: lanes 0..31 hold eidx[0][b][nb..nb+7][*] (128 ints),
  // lanes 32..63 hold eidx[1][...]; int4 per lane. Point p, slot k lives in
  // lane (p*16+k)>>2 component (p*16+k)&3.
  const int* e0 = eidx + (b*N_ + nb)*K_;
  const int* e1 = eidx + B_*N_*K_ + (b*N_ + nb)*K_;
  const int4 r = (lane < 32) ? *(const int4*)(e0 + lane*4)
                             : *(const int4*)(e1 + (lane - 32)*4);

  float ssum = 0.f, ssq = 0.f;
  __shared__ float redS[4][64], redQ[4][64];

  for (int p = 0; p < 8; ++p){
    float hmax = -1e30f, hmin = 1e30f;
    #pragma unroll
    for (int k = 0; k < 16; ++k){
      const int flat = p*16 + k;
      const int src  = flat >> 2;
      const int jj = __shfl(comp4(r, flat & 3), src);
      const int ii = __shfl(comp4(r, flat & 3), 32 + src);
      const float h = bf2f(ub[(size_t)ii*64 + lane]) + bf2f(vb[(size_t)jj*64 + lane]);
      hmax = fmaxf(hmax, h);
      hmin = fminf(hmin, h);
      ssum += h;
      ssq = fmaf(h, h, ssq);
    }
    const int n = nb + p;
    wmaxo[((size_t)(b*N_ + n))*64 + lane] = f2bf(hmax);
    wmino[((size_t)(b*N_ + n))*64 + lane] = f2bf(hmin);
  }

  redS[wid][lane] = ssum;
  redQ[wid][lane] = ssq;
  __syncthreads();
  if (tid < 64){
    atomicAdd(&stats[tid], redS[0][tid] + redS[1][tid] + redS[2][tid] + redS[3][tid]);
  } else if (tid < 128){
    const int c = tid - 64;
    atomicAdd(&stats[64 + c], redQ[0][c] + redQ[1][c] + redQ[2][c] + redQ[3][c]);
  }
}

// ---------------- K3: finalize BN affine: sct[c]=scale, sct[64+c]=shift ----------
__global__ void k3_finalize(const float* __restrict__ stats,
                            const float* __restrict__ gamma,
                            const float* __restrict__ beta,
                            float* __restrict__ sct){
  const int c = threadIdx.x;
  const float inv = 1.0f / (float)(B_*N_*K_);
  const float mean = stats[c] * inv;
  const float var  = stats[64+c] * inv - mean*mean;
  const float s = gamma[c] * rsqrtf(var + EPSBN);
  sct[c] = s;
  sct[64+c] = beta[c] - mean*s;
}

// ---------------- K4: MFMA weighted conv ------------------------------------------
// grid (N/64, B), block 256 (4 waves). Wave w: o in [w*32, w*32+32), n-tile 64.
// out[o][n] = sum_j wgt[j][n] * (Wj x hbn_shift_j)[o][n] + bias
__global__ __launch_bounds__(256) void k4_mfma(const u16* __restrict__ wmaxo,
                                               const u16* __restrict__ wmino,
                                               const float* __restrict__ sct,
                                               const float* __restrict__ coords,
                                               const u16* __restrict__ wbf,
                                               const float* __restrict__ bconv,
                                               float* __restrict__ out){
  const int n0 = blockIdx.x * 64;
  const int b  = blockIdx.y;
  const int tid = threadIdx.x;
  const int w = tid >> 6, lane = tid & 63;
  const int r15 = lane & 15, kg = lane >> 4;

  __shared__ u16 hl[72*72];     // [m_local][c], row stride 72 (pad) -> 10.4 KB
  __shared__ float wgt[9*64];   // [j][n] Gaussian weights

  // --- build hbn tile: h = leaky(s*max_or_min + t), rows m = n0-4 .. n0+67
  {
    const int c = tid & 63;
    const float s = sct[c], t = sct[64+c];
    const u16* src = ((s >= 0.f) ? wmaxo : wmino) + (size_t)b*N_*64 + c;
    #pragma unroll
    for (int it = 0; it < 18; ++it){
      const int ml = (tid >> 6) + it*4;
      const int m = n0 - 4 + ml;
      float hv = 0.f;
      if (m >= 0 && m < N_){
        hv = fmaf(s, bf2f(src[(size_t)m*64]), t);
        hv = (hv >= 0.f) ? hv : NEG*hv;
      }
      hl[ml*72 + c] = f2bf(hv);
    }
  }
  // --- build Gaussian weights wgt[j][n]
  for (int idx = tid; idx < 576; idx += 256){
    const int j = idx >> 6, n = idx & 63;
    const int mc = n0 + n, mt = mc + j - 4;
    float wv = 0.f;
    if (mt >= 0 && mt < N_){
      float d2 = 0.f;
      #pragma unroll
      for (int d = 0; d < 3; ++d){
        const float dd = coords[(b*3+d)*N_ + mt] - coords[(b*3+d)*N_ + mc];
        d2 = fmaf(dd, dd, d2);
      }
      wv = __expf(-INV_SIG2 * d2);
    }
    wgt[idx] = wv;
  }
  __syncthreads();

  // --- MFMA main loop over taps j
  const u16* abase = wbf + ((w*32 + r15)*64 + kg*8);   // + j*8192 + of*1024 + cc
  const u16* hbase = &hl[r15*72 + kg*8];               // + (nf*16 + j)*72 + cc
  f32x4 acc[2][4] = {};
  const f32x4 zero = {0.f, 0.f, 0.f, 0.f};

  for (int j = 0; j < 9; ++j){
    float wj[4];
    #pragma unroll
    for (int nf = 0; nf < 4; ++nf) wj[nf] = wgt[j*64 + nf*16 + r15];
    short8 bfr[4][2];
    #pragma unroll
    for (int nf = 0; nf < 4; ++nf){
      bfr[nf][0] = *(const short8*)&hbase[(nf*16 + j)*72];
      bfr[nf][1] = *(const short8*)&hbase[(nf*16 + j)*72 + 32];
    }
    #pragma unroll
    for (int of = 0; of < 2; ++of){
      const short8 a0 = *(const short8*)&abase[j*8192 + of*1024];
      const short8 a1 = *(const short8*)&abase[j*8192 + of*1024 + 32];
      #pragma unroll
      for (int nf = 0; nf < 4; ++nf){
        f32x4 p = __builtin_amdgcn_mfma_f32_16x16x32_bf16(a0, bfr[nf][0], zero, 0, 0, 0);
        p = __builtin_amdgcn_mfma_f32_16x16x32_bf16(a1, bfr[nf][1], p, 0, 0, 0);
        #pragma unroll
        for (int r = 0; r < 4; ++r)
          acc[of][nf][r] = fmaf(wj[nf], p[r], acc[of][nf][r]);
      }
    }
  }

  // --- epilogue: D layout col = lane&15, row = (lane>>4)*4 + reg
  #pragma unroll
  for (int of = 0; of < 2; ++of){
    #pragma unroll
    for (int r = 0; r < 4; ++r){
      const int o = w*32 + of*16 + kg*4 + r;
      const float bs = bconv[o];
      float* dst = &out[(size_t)(b*128 + o)*N_ + n0 + r15];
      #pragma unroll
      for (int nf = 0; nf < 4; ++nf)
        dst[nf*16] = acc[of][nf][r] + bs;
    }
  }
}

extern "C" void kernel_launch(void* const* d_in, const int* in_sizes, int n_in,
                              void* d_out, int out_size, void* d_ws, size_t ws_size,
                              hipStream_t stream){
  const float* x      = (const float*)d_in[0];
  const float* coords = (const float*)d_in[1];
  const int*   eidx   = (const int*)  d_in[2];
  const float* we     = (const float*)d_in[3];
  const float* gamma  = (const float*)d_in[4];
  const float* beta   = (const float*)d_in[5];
  const float* wconv  = (const float*)d_in[6];
  const float* bconv  = (const float*)d_in[7];
  float* out = (float*)d_out;
  char* ws = (char*)d_ws;
  // ws layout (bytes): u[8.39MB] v[8.39MB] wmax[8.39MB] wmin[8.39MB] stats[512] sct[512] wbf[147KB]
  u16* u     = (u16*)(ws);
  u16* v     = (u16*)(ws + 8388608);
  u16* wmax_ = (u16*)(ws + 16777216);
  u16* wmin_ = (u16*)(ws + 25165824);
  float* stats = (float*)(ws + 33554432);
  float* sct   = (float*)(ws + 33554944);
  u16* wbf     = (u16*)(ws + 33555456);

  hipMemsetAsync(stats, 0, 512, stream);
  k0_wprep<<<288, 256, 0, stream>>>(wconv, wbf);
  k1_uv<<<dim3(N_/128, B_), 256, 0, stream>>>(x, we, u, v);
  k2_gather<<<2048, 256, 0, stream>>>(u, v, eidx, wmax_, wmin_, stats);
  k3_finalize<<<1, 64, 0, stream>>>(stats, gamma, beta, sct);
  k4_mfma<<<dim3(N_/64, B_), 256, 0, stream>>>(wmax_, wmin_, sct, coords, wbf, bconv, out);
}

// Round 6
// 150.583 us; speedup vs baseline: 1.4388x; 1.0107x over previous
//
#include <hip/hip_runtime.h>
#include <hip/hip_bf16.h>

#define B_ 4
#define N_ 16384
#define K_ 16
#define NEG 0.2f
#define EPSBN 1e-5f
#define INV_SIG2 2500.0f

typedef unsigned short u16;
typedef unsigned int   u32;
typedef __attribute__((ext_vector_type(8))) short short8;
typedef __attribute__((ext_vector_type(4))) float f32x4;

__device__ __forceinline__ float bf2f(u16 h){
  return __uint_as_float(((u32)h) << 16);
}
__device__ __forceinline__ u16 f2bf(float f){
  u32 x = __float_as_uint(f);
  x += 0x7fffu + ((x >> 16) & 1u);
  return (u16)(x >> 16);
}
__device__ __forceinline__ int comp4(int4 r, int c){
  return c == 0 ? r.x : (c == 1 ? r.y : (c == 2 ? r.z : r.w));
}

// ---------------- K0: wconv [o][c][j] fp32 -> wbf [j][o][c] bf16 ----------------
__global__ void k0_wprep(const float* __restrict__ wconv, u16* __restrict__ wbf){
  const int idx = blockIdx.x * 256 + threadIdx.x;
  if (idx < 9*128*64){
    const int j = idx >> 13;
    const int rem = idx & 8191;
    const int o = rem >> 6, c = rem & 63;
    wbf[idx] = f2bf(wconv[(o*64 + c)*9 + j]);
  }
}

// ---------------- K1: u = (W1-W2)^T x, v = W2^T x, stored [B][N][64] bf16 --------
__global__ __launch_bounds__(256) void k1_uv(const float* __restrict__ x,
                                             const float* __restrict__ we,
                                             u16* __restrict__ uo,
                                             u16* __restrict__ vo){
  const int n0 = blockIdx.x * 128;
  const int b  = blockIdx.y;
  __shared__ u16   Wl[64*128];   // [c'][r] bf16, r<64 -> WA=W1-W2, r>=64 -> WB=W2
  __shared__ float Xl[64*128];   // [c'][n]
  const int tid = threadIdx.x;
  for (int idx = tid; idx < 64*128; idx += 256){
    const int cp = idx >> 7, r = idx & 127;
    float w;
    if (r < 64) w = we[r*128 + cp] - we[r*128 + 64 + cp];
    else        w = we[(r-64)*128 + 64 + cp];
    Wl[cp*128 + r] = f2bf(w);
  }
  for (int idx = tid; idx < 64*128; idx += 256){
    const int cp = idx >> 7, nl = idx & 127;
    Xl[cp*128 + nl] = x[(b*64 + cp)*N_ + n0 + nl];
  }
  __syncthreads();
  const int tr = tid & 15, tc = tid >> 4;
  float acc[8][8];
  #pragma unroll
  for (int i=0;i<8;++i)
    #pragma unroll
    for (int j=0;j<8;++j) acc[i][j] = 0.f;
  for (int cp=0; cp<64; ++cp){
    const uint4 wv = *(const uint4*)&Wl[cp*128 + tr*8];
    float wr[8];
    wr[0]=__uint_as_float(wv.x<<16); wr[1]=__uint_as_float(wv.x & 0xffff0000u);
    wr[2]=__uint_as_float(wv.y<<16); wr[3]=__uint_as_float(wv.y & 0xffff0000u);
    wr[4]=__uint_as_float(wv.z<<16); wr[5]=__uint_as_float(wv.z & 0xffff0000u);
    wr[6]=__uint_as_float(wv.w<<16); wr[7]=__uint_as_float(wv.w & 0xffff0000u);
    const float4 x0 = *(const float4*)&Xl[cp*128 + tc*8];
    const float4 x1 = *(const float4*)&Xl[cp*128 + tc*8 + 4];
    const float xr[8] = {x0.x,x0.y,x0.z,x0.w,x1.x,x1.y,x1.z,x1.w};
    #pragma unroll
    for (int i=0;i<8;++i)
      #pragma unroll
      for (int j=0;j<8;++j)
        acc[i][j] = fmaf(wr[i], xr[j], acc[i][j]);
  }
  u16* dst = (tr < 8) ? uo : vo;
  const int cb = (tr & 7) * 8;
  #pragma unroll
  for (int ni=0; ni<8; ++ni){
    const int n = n0 + tc*8 + ni;
    u32 p0 = (u32)f2bf(acc[0][ni]) | ((u32)f2bf(acc[1][ni]) << 16);
    u32 p1 = (u32)f2bf(acc[2][ni]) | ((u32)f2bf(acc[3][ni]) << 16);
    u32 p2 = (u32)f2bf(acc[4][ni]) | ((u32)f2bf(acc[5][ni]) << 16);
    u32 p3 = (u32)f2bf(acc[6][ni]) | ((u32)f2bf(acc[7][ni]) << 16);
    *(uint4*)&dst[(b*N_ + n)*64 + cb] = make_uint4(p0,p1,p2,p3);
  }
}

// ---------------- K2 v6: gather h = u[i]+v[j]; per-(b,n) max/min; stats ----------
// Scalarized index path: gather indices are wave-uniform, so pull them with
// v_readlane into SGPRs; row bases become SALU math and gathers compile to
// saddr-form global_load_ushort with fixed voffset = lane*2. No ds_bpermute,
// no per-load VALU addressing; 32 independent 1-VGPR loads per point hoisted
// ahead of the unpack/reduce chain.
__global__ __launch_bounds__(256) void k2_gather(const u16* __restrict__ uo,
                                                 const u16* __restrict__ vo,
                                                 const int* __restrict__ eidx,
                                                 u16* __restrict__ wmaxo,
                                                 u16* __restrict__ wmino,
                                                 float* __restrict__ stats){
  const int bid = blockIdx.x;
  const int xcd = bid & 7;
  const int b   = xcd >> 1;
  const int n0  = ((bid >> 3) + (xcd & 1)*256) * 32;
  const int tid = threadIdx.x;
  const int wid = tid >> 6, lane = tid & 63;
  const int nb  = n0 + wid*8;          // wave's 8 points
  const u16* ub = uo + (size_t)b*N_*64 + lane;
  const u16* vb = vo + (size_t)b*N_*64 + lane;

  // prefetch edge indices: lanes 0..31 hold eidx[0][b][nb..nb+7][*] (128 ints),
  // lanes 32..63 hold eidx[1][...]; int4 per lane. Point p, slot k lives in
  // lane (p*16+k)>>2 component (p*16+k)&3.
  const int* e0 = eidx + (b*N_ + nb)*K_;
  const int* e1 = eidx + B_*N_*K_ + (b*N_ + nb)*K_;
  const int4 r = (lane < 32) ? *(const int4*)(e0 + lane*4)
                             : *(const int4*)(e1 + (lane - 32)*4);

  float ssum = 0.f, ssq = 0.f;
  __shared__ float redS[4][64], redQ[4][64];

  for (int p = 0; p < 8; ++p){
    const int base = p*4;                  // uniform (SGPR) readlane source base
    u16 hu[16], hv[16];
    #pragma unroll
    for (int k = 0; k < 16; ++k){
      const int jj = __builtin_amdgcn_readlane(comp4(r, k & 3), base + (k >> 2));
      const int ii = __builtin_amdgcn_readlane(comp4(r, k & 3), 32 + base + (k >> 2));
      hu[k] = ub[(size_t)ii*64];
      hv[k] = vb[(size_t)jj*64];
    }
    float hmax = -1e30f, hmin = 1e30f;
    #pragma unroll
    for (int k = 0; k < 16; ++k){
      const float h = bf2f(hu[k]) + bf2f(hv[k]);
      hmax = fmaxf(hmax, h);
      hmin = fminf(hmin, h);
      ssum += h;
      ssq = fmaf(h, h, ssq);
    }
    const int n = nb + p;
    wmaxo[((size_t)(b*N_ + n))*64 + lane] = f2bf(hmax);
    wmino[((size_t)(b*N_ + n))*64 + lane] = f2bf(hmin);
  }

  redS[wid][lane] = ssum;
  redQ[wid][lane] = ssq;
  __syncthreads();
  if (tid < 64){
    atomicAdd(&stats[tid], redS[0][tid] + redS[1][tid] + redS[2][tid] + redS[3][tid]);
  } else if (tid < 128){
    const int c = tid - 64;
    atomicAdd(&stats[64 + c], redQ[0][c] + redQ[1][c] + redQ[2][c] + redQ[3][c]);
  }
}

// ---------------- K3: finalize BN affine: sct[c]=scale, sct[64+c]=shift ----------
__global__ void k3_finalize(const float* __restrict__ stats,
                            const float* __restrict__ gamma,
                            const float* __restrict__ beta,
                            float* __restrict__ sct){
  const int c = threadIdx.x;
  const float inv = 1.0f / (float)(B_*N_*K_);
  const float mean = stats[c] * inv;
  const float var  = stats[64+c] * inv - mean*mean;
  const float s = gamma[c] * rsqrtf(var + EPSBN);
  sct[c] = s;
  sct[64+c] = beta[c] - mean*s;
}

// ---------------- K4: MFMA weighted conv ------------------------------------------
// grid (N/64, B), block 256 (4 waves). Wave w: o in [w*32, w*32+32), n-tile 64.
// out[o][n] = sum_j wgt[j][n] * (Wj x hbn_shift_j)[o][n] + bias
__global__ __launch_bounds__(256) void k4_mfma(const u16* __restrict__ wmaxo,
                                               const u16* __restrict__ wmino,
                                               const float* __restrict__ sct,
                                               const float* __restrict__ coords,
                                               const u16* __restrict__ wbf,
                                               const float* __restrict__ bconv,
                                               float* __restrict__ out){
  const int n0 = blockIdx.x * 64;
  const int b  = blockIdx.y;
  const int tid = threadIdx.x;
  const int w = tid >> 6, lane = tid & 63;
  const int r15 = lane & 15, kg = lane >> 4;

  __shared__ u16 hl[72*72];     // [m_local][c], row stride 72 (pad) -> 10.4 KB
  __shared__ float wgt[9*64];   // [j][n] Gaussian weights

  // --- build hbn tile: h = leaky(s*max_or_min + t), rows m = n0-4 .. n0+67
  {
    const int c = tid & 63;
    const float s = sct[c], t = sct[64+c];
    const u16* src = ((s >= 0.f) ? wmaxo : wmino) + (size_t)b*N_*64 + c;
    #pragma unroll
    for (int it = 0; it < 18; ++it){
      const int ml = (tid >> 6) + it*4;
      const int m = n0 - 4 + ml;
      float hv = 0.f;
      if (m >= 0 && m < N_){
        hv = fmaf(s, bf2f(src[(size_t)m*64]), t);
        hv = (hv >= 0.f) ? hv : NEG*hv;
      }
      hl[ml*72 + c] = f2bf(hv);
    }
  }
  // --- build Gaussian weights wgt[j][n]
  for (int idx = tid; idx < 576; idx += 256){
    const int j = idx >> 6, n = idx & 63;
    const int mc = n0 + n, mt = mc + j - 4;
    float wv = 0.f;
    if (mt >= 0 && mt < N_){
      float d2 = 0.f;
      #pragma unroll
      for (int d = 0; d < 3; ++d){
        const float dd = coords[(b*3+d)*N_ + mt] - coords[(b*3+d)*N_ + mc];
        d2 = fmaf(dd, dd, d2);
      }
      wv = __expf(-INV_SIG2 * d2);
    }
    wgt[idx] = wv;
  }
  __syncthreads();

  // --- MFMA main loop over taps j
  const u16* abase = wbf + ((w*32 + r15)*64 + kg*8);   // + j*8192 + of*1024 + cc
  const u16* hbase = &hl[r15*72 + kg*8];               // + (nf*16 + j)*72 + cc
  f32x4 acc[2][4] = {};
  const f32x4 zero = {0.f, 0.f, 0.f, 0.f};

  for (int j = 0; j < 9; ++j){
    float wj[4];
    #pragma unroll
    for (int nf = 0; nf < 4; ++nf) wj[nf] = wgt[j*64 + nf*16 + r15];
    short8 bfr[4][2];
    #pragma unroll
    for (int nf = 0; nf < 4; ++nf){
      bfr[nf][0] = *(const short8*)&hbase[(nf*16 + j)*72];
      bfr[nf][1] = *(const short8*)&hbase[(nf*16 + j)*72 + 32];
    }
    #pragma unroll
    for (int of = 0; of < 2; ++of){
      const short8 a0 = *(const short8*)&abase[j*8192 + of*1024];
      const short8 a1 = *(const short8*)&abase[j*8192 + of*1024 + 32];
      #pragma unroll
      for (int nf = 0; nf < 4; ++nf){
        f32x4 p = __builtin_amdgcn_mfma_f32_16x16x32_bf16(a0, bfr[nf][0], zero, 0, 0, 0);
        p = __builtin_amdgcn_mfma_f32_16x16x32_bf16(a1, bfr[nf][1], p, 0, 0, 0);
        #pragma unroll
        for (int r = 0; r < 4; ++r)
          acc[of][nf][r] = fmaf(wj[nf], p[r], acc[of][nf][r]);
      }
    }
  }

  // --- epilogue: D layout col = lane&15, row = (lane>>4)*4 + reg
  #pragma unroll
  for (int of = 0; of < 2; ++of){
    #pragma unroll
    for (int r = 0; r < 4; ++r){
      const int o = w*32 + of*16 + kg*4 + r;
      const float bs = bconv[o];
      float* dst = &out[(size_t)(b*128 + o)*N_ + n0 + r15];
      #pragma unroll
      for (int nf = 0; nf < 4; ++nf)
        dst[nf*16] = acc[of][nf][r] + bs;
    }
  }
}

extern "C" void kernel_launch(void* const* d_in, const int* in_sizes, int n_in,
                              void* d_out, int out_size, void* d_ws, size_t ws_size,
                              hipStream_t stream){
  const float* x      = (const float*)d_in[0];
  const float* coords = (const float*)d_in[1];
  const int*   eidx   = (const int*)  d_in[2];
  const float* we     = (const float*)d_in[3];
  const float* gamma  = (const float*)d_in[4];
  const float* beta   = (const float*)d_in[5];
  const float* wconv  = (const float*)d_in[6];
  const float* bconv  = (const float*)d_in[7];
  float* out = (float*)d_out;
  char* ws = (char*)d_ws;
  // ws layout (bytes): u[8.39MB] v[8.39MB] wmax[8.39MB] wmin[8.39MB] stats[512] sct[512] wbf[147KB]
  u16* u     = (u16*)(ws);
  u16* v     = (u16*)(ws + 8388608);
  u16* wmax_ = (u16*)(ws + 16777216);
  u16* wmin_ = (u16*)(ws + 25165824);
  float* stats = (float*)(ws + 33554432);
  float* sct   = (float*)(ws + 33554944);
  u16* wbf     = (u16*)(ws + 33555456);

  hipMemsetAsync(stats, 0, 512, stream);
  k0_wprep<<<288, 256, 0, stream>>>(wconv, wbf);
  k1_uv<<<dim3(N_/128, B_), 256, 0, stream>>>(x, we, u, v);
  k2_gather<<<2048, 256, 0, stream>>>(u, v, eidx, wmax_, wmin_, stats);
  k3_finalize<<<1, 64, 0, stream>>>(stats, gamma, beta, sct);
  k4_mfma<<<dim3(N_/64, B_), 256, 0, stream>>>(wmax_, wmin_, sct, coords, wbf, bconv, out);
}

// Round 7
// 147.384 us; speedup vs baseline: 1.4701x; 1.0217x over previous
//
#include <hip/hip_runtime.h>
#include <hip/hip_bf16.h>

#define B_ 4
#define N_ 16384
#define K_ 16
#define NEG 0.2f
#define EPSBN 1e-5f
#define INV_SIG2 2500.0f

typedef unsigned short u16;
typedef unsigned int   u32;
typedef __attribute__((ext_vector_type(8))) short short8;
typedef __attribute__((ext_vector_type(4))) float f32x4;

__device__ __forceinline__ float bf2f(u16 h){
  return __uint_as_float(((u32)h) << 16);
}
__device__ __forceinline__ u16 f2bf(float f){
  u32 x = __float_as_uint(f);
  x += 0x7fffu + ((x >> 16) & 1u);
  return (u16)(x >> 16);
}
__device__ __forceinline__ int comp4(int4 r, int c){
  return c == 0 ? r.x : (c == 1 ? r.y : (c == 2 ? r.z : r.w));
}

// u/v/wmax/wmin layout: [half][B][N][32] u16 — each (batch, channel-half)
// partition is 1MB (u) + 1MB (v) -> fits one XCD's 4MB L2.

// ---------------- K0: wconv [o][c][j] fp32 -> wbf [j][o][c] bf16 ----------------
__global__ void k0_wprep(const float* __restrict__ wconv, u16* __restrict__ wbf){
  const int idx = blockIdx.x * 256 + threadIdx.x;
  if (idx < 9*128*64){
    const int j = idx >> 13;
    const int rem = idx & 8191;
    const int o = rem >> 6, c = rem & 63;
    wbf[idx] = f2bf(wconv[(o*64 + c)*9 + j]);
  }
}

// ---------------- K1: u = (W1-W2)^T x, v = W2^T x ---------------------------------
__global__ __launch_bounds__(256) void k1_uv(const float* __restrict__ x,
                                             const float* __restrict__ we,
                                             u16* __restrict__ uo,
                                             u16* __restrict__ vo){
  const int n0 = blockIdx.x * 128;
  const int b  = blockIdx.y;
  __shared__ u16   Wl[64*128];   // [c'][r] bf16, r<64 -> WA=W1-W2, r>=64 -> WB=W2
  __shared__ float Xl[64*128];   // [c'][n]
  const int tid = threadIdx.x;
  for (int idx = tid; idx < 64*128; idx += 256){
    const int cp = idx >> 7, r = idx & 127;
    float w;
    if (r < 64) w = we[r*128 + cp] - we[r*128 + 64 + cp];
    else        w = we[(r-64)*128 + 64 + cp];
    Wl[cp*128 + r] = f2bf(w);
  }
  for (int idx = tid; idx < 64*128; idx += 256){
    const int cp = idx >> 7, nl = idx & 127;
    Xl[cp*128 + nl] = x[(b*64 + cp)*N_ + n0 + nl];
  }
  __syncthreads();
  const int tr = tid & 15, tc = tid >> 4;
  float acc[8][8];
  #pragma unroll
  for (int i=0;i<8;++i)
    #pragma unroll
    for (int j=0;j<8;++j) acc[i][j] = 0.f;
  for (int cp=0; cp<64; ++cp){
    const uint4 wv = *(const uint4*)&Wl[cp*128 + tr*8];
    float wr[8];
    wr[0]=__uint_as_float(wv.x<<16); wr[1]=__uint_as_float(wv.x & 0xffff0000u);
    wr[2]=__uint_as_float(wv.y<<16); wr[3]=__uint_as_float(wv.y & 0xffff0000u);
    wr[4]=__uint_as_float(wv.z<<16); wr[5]=__uint_as_float(wv.z & 0xffff0000u);
    wr[6]=__uint_as_float(wv.w<<16); wr[7]=__uint_as_float(wv.w & 0xffff0000u);
    const float4 x0 = *(const float4*)&Xl[cp*128 + tc*8];
    const float4 x1 = *(const float4*)&Xl[cp*128 + tc*8 + 4];
    const float xr[8] = {x0.x,x0.y,x0.z,x0.w,x1.x,x1.y,x1.z,x1.w};
    #pragma unroll
    for (int i=0;i<8;++i)
      #pragma unroll
      for (int j=0;j<8;++j)
        acc[i][j] = fmaf(wr[i], xr[j], acc[i][j]);
  }
  // store: channels c = (tr&7)*8 .. +8 of u (tr<8) or v (tr>=8), new layout
  u16* arr = (tr < 8) ? uo : vo;
  const int c0 = (tr & 7) * 8;
  const int half = c0 >> 5;             // uniform per tr
  const int cb = c0 & 31;
  u16* dstb = arr + ((size_t)(half*B_ + b))*N_*32 + cb;
  #pragma unroll
  for (int ni=0; ni<8; ++ni){
    const int n = n0 + tc*8 + ni;
    u32 p0 = (u32)f2bf(acc[0][ni]) | ((u32)f2bf(acc[1][ni]) << 16);
    u32 p1 = (u32)f2bf(acc[2][ni]) | ((u32)f2bf(acc[3][ni]) << 16);
    u32 p2 = (u32)f2bf(acc[4][ni]) | ((u32)f2bf(acc[5][ni]) << 16);
    u32 p3 = (u32)f2bf(acc[6][ni]) | ((u32)f2bf(acc[7][ni]) << 16);
    *(uint4*)&dstb[(size_t)n*32] = make_uint4(p0,p1,p2,p3);
  }
}

// ---------------- K2 v7: channel-split gather; per-XCD L2-resident source --------
// 4096 blocks x 256 thr. Partition p8 = bid&7 -> (b = p8>>1, half = p8&1); each
// XCD gathers only from its 2MB u/v partition. Wave processes point PAIRS:
// lanes 0..31 = point A's 32 channels, lanes 32..63 = point B's.
__global__ __launch_bounds__(256) void k2_gather(const u16* __restrict__ uo,
                                                 const u16* __restrict__ vo,
                                                 const int* __restrict__ eidx,
                                                 u16* __restrict__ wmaxo,
                                                 u16* __restrict__ wmino,
                                                 float* __restrict__ stats){
  const int bid = blockIdx.x;
  const int p8  = bid & 7;
  const int b   = p8 >> 1;
  const int h   = p8 & 1;
  const int n0  = (bid >> 3) * 32;
  const int tid = threadIdx.x;
  const int wid = tid >> 6, lane = tid & 63;
  const int ch = lane & 31, a = lane >> 5;   // a: which point of the pair
  const int nb  = n0 + wid*8;                // wave's 8 points
  const size_t pbase = ((size_t)(h*B_ + b))*N_*32;
  const u16* ub = uo + pbase + ch;
  const u16* vb = vo + pbase + ch;
  u16* wmx = wmaxo + pbase + ch;
  u16* wmn = wmino + pbase + ch;

  // prefetch edge indices: lanes 0..31 hold eidx[0][b][nb..nb+7][*] (128 ints),
  // lanes 32..63 hold eidx[1][...]; int4 per lane. Point p, slot k lives in
  // lane (p*16+k)>>2 component (p*16+k)&3 of the respective half.
  const int* e0 = eidx + (b*N_ + nb)*K_;
  const int* e1 = eidx + B_*N_*K_ + (b*N_ + nb)*K_;
  const int4 r = (lane < 32) ? *(const int4*)(e0 + lane*4)
                             : *(const int4*)(e1 + (lane - 32)*4);

  float ssum = 0.f, ssq = 0.f;
  __shared__ float redS[4][64], redQ[4][64];

  for (int pr = 0; pr < 4; ++pr){
    const int srcb = (pr*2 + a)*4;           // uniform per half-wave
    float hmax = -1e30f, hmin = 1e30f;
    #pragma unroll
    for (int k = 0; k < 16; ++k){
      const int src = srcb + (k >> 2);
      const int jj = __shfl(comp4(r, k & 3), src);        // from j-half (lanes 0..31)
      const int ii = __shfl(comp4(r, k & 3), 32 + src);   // from i-half (lanes 32..63)
      const float hv = bf2f(ub[(size_t)ii*32]) + bf2f(vb[(size_t)jj*32]);
      hmax = fmaxf(hmax, hv);
      hmin = fminf(hmin, hv);
      ssum += hv;
      ssq = fmaf(hv, hv, ssq);
    }
    const int n = nb + pr*2 + a;
    wmx[(size_t)n*32] = f2bf(hmax);
    wmn[(size_t)n*32] = f2bf(hmin);
  }

  redS[wid][lane] = ssum;
  redQ[wid][lane] = ssq;
  __syncthreads();
  // global channel = h*32 + ch; combine 4 waves x 2 pair-halves
  if (tid < 32){
    float s = 0.f;
    #pragma unroll
    for (int w2 = 0; w2 < 4; ++w2) s += redS[w2][tid] + redS[w2][tid + 32];
    atomicAdd(&stats[h*32 + tid], s);
  } else if (tid < 64){
    const int c2 = tid - 32;
    float q = 0.f;
    #pragma unroll
    for (int w2 = 0; w2 < 4; ++w2) q += redQ[w2][c2] + redQ[w2][c2 + 32];
    atomicAdd(&stats[64 + h*32 + c2], q);
  }
}

// ---------------- K3: finalize BN affine: sct[c]=scale, sct[64+c]=shift ----------
__global__ void k3_finalize(const float* __restrict__ stats,
                            const float* __restrict__ gamma,
                            const float* __restrict__ beta,
                            float* __restrict__ sct){
  const int c = threadIdx.x;
  const float inv = 1.0f / (float)(B_*N_*K_);
  const float mean = stats[c] * inv;
  const float var  = stats[64+c] * inv - mean*mean;
  const float s = gamma[c] * rsqrtf(var + EPSBN);
  sct[c] = s;
  sct[64+c] = beta[c] - mean*s;
}

// ---------------- K4: MFMA weighted conv ------------------------------------------
// grid (N/64, B), block 256 (4 waves). Wave w: o in [w*32, w*32+32), n-tile 64.
// out[o][n] = sum_j wgt[j][n] * (Wj x hbn_shift_j)[o][n] + bias
__global__ __launch_bounds__(256) void k4_mfma(const u16* __restrict__ wmaxo,
                                               const u16* __restrict__ wmino,
                                               const float* __restrict__ sct,
                                               const float* __restrict__ coords,
                                               const u16* __restrict__ wbf,
                                               const float* __restrict__ bconv,
                                               float* __restrict__ out){
  const int n0 = blockIdx.x * 64;
  const int b  = blockIdx.y;
  const int tid = threadIdx.x;
  const int w = tid >> 6, lane = tid & 63;
  const int r15 = lane & 15, kg = lane >> 4;

  __shared__ u16 hl[72*72];     // [m_local][c], row stride 72 (pad) -> 10.4 KB
  __shared__ float wgt[9*64];   // [j][n] Gaussian weights

  // --- build hbn tile: h = leaky(s*max_or_min + t), rows m = n0-4 .. n0+67
  {
    const int c = tid & 63;
    const float s = sct[c], t = sct[64+c];
    const u16* src = ((s >= 0.f) ? wmaxo : wmino)
                   + ((size_t)((c >> 5)*B_ + b))*N_*32 + (c & 31);
    #pragma unroll
    for (int it = 0; it < 18; ++it){
      const int ml = (tid >> 6) + it*4;
      const int m = n0 - 4 + ml;
      float hv = 0.f;
      if (m >= 0 && m < N_){
        hv = fmaf(s, bf2f(src[(size_t)m*32]), t);
        hv = (hv >= 0.f) ? hv : NEG*hv;
      }
      hl[ml*72 + c] = f2bf(hv);
    }
  }
  // --- build Gaussian weights wgt[j][n]
  for (int idx = tid; idx < 576; idx += 256){
    const int j = idx >> 6, n = idx & 63;
    const int mc = n0 + n, mt = mc + j - 4;
    float wv = 0.f;
    if (mt >= 0 && mt < N_){
      float d2 = 0.f;
      #pragma unroll
      for (int d = 0; d < 3; ++d){
        const float dd = coords[(b*3+d)*N_ + mt] - coords[(b*3+d)*N_ + mc];
        d2 = fmaf(dd, dd, d2);
      }
      wv = __expf(-INV_SIG2 * d2);
    }
    wgt[idx] = wv;
  }
  __syncthreads();

  // --- MFMA main loop over taps j
  const u16* abase = wbf + ((w*32 + r15)*64 + kg*8);   // + j*8192 + of*1024 + cc
  const u16* hbase = &hl[r15*72 + kg*8];               // + (nf*16 + j)*72 + cc
  f32x4 acc[2][4] = {};
  const f32x4 zero = {0.f, 0.f, 0.f, 0.f};

  for (int j = 0; j < 9; ++j){
    float wj[4];
    #pragma unroll
    for (int nf = 0; nf < 4; ++nf) wj[nf] = wgt[j*64 + nf*16 + r15];
    short8 bfr[4][2];
    #pragma unroll
    for (int nf = 0; nf < 4; ++nf){
      bfr[nf][0] = *(const short8*)&hbase[(nf*16 + j)*72];
      bfr[nf][1] = *(const short8*)&hbase[(nf*16 + j)*72 + 32];
    }
    #pragma unroll
    for (int of = 0; of < 2; ++of){
      const short8 a0 = *(const short8*)&abase[j*8192 + of*1024];
      const short8 a1 = *(const short8*)&abase[j*8192 + of*1024 + 32];
      #pragma unroll
      for (int nf = 0; nf < 4; ++nf){
        f32x4 p = __builtin_amdgcn_mfma_f32_16x16x32_bf16(a0, bfr[nf][0], zero, 0, 0, 0);
        p = __builtin_amdgcn_mfma_f32_16x16x32_bf16(a1, bfr[nf][1], p, 0, 0, 0);
        #pragma unroll
        for (int r = 0; r < 4; ++r)
          acc[of][nf][r] = fmaf(wj[nf], p[r], acc[of][nf][r]);
      }
    }
  }

  // --- epilogue: D layout col = lane&15, row = (lane>>4)*4 + reg
  #pragma unroll
  for (int of = 0; of < 2; ++of){
    #pragma unroll
    for (int r = 0; r < 4; ++r){
      const int o = w*32 + of*16 + kg*4 + r;
      const float bs = bconv[o];
      float* dst = &out[(size_t)(b*128 + o)*N_ + n0 + r15];
      #pragma unroll
      for (int nf = 0; nf < 4; ++nf)
        dst[nf*16] = acc[of][nf][r] + bs;
    }
  }
}

extern "C" void kernel_launch(void* const* d_in, const int* in_sizes, int n_in,
                              void* d_out, int out_size, void* d_ws, size_t ws_size,
                              hipStream_t stream){
  const float* x      = (const float*)d_in[0];
  const float* coords = (const float*)d_in[1];
  const int*   eidx   = (const int*)  d_in[2];
  const float* we     = (const float*)d_in[3];
  const float* gamma  = (const float*)d_in[4];
  const float* beta   = (const float*)d_in[5];
  const float* wconv  = (const float*)d_in[6];
  const float* bconv  = (const float*)d_in[7];
  float* out = (float*)d_out;
  char* ws = (char*)d_ws;
  // ws layout (bytes): u[8.39MB] v[8.39MB] wmax[8.39MB] wmin[8.39MB] stats[512] sct[512] wbf[147KB]
  u16* u     = (u16*)(ws);
  u16* v     = (u16*)(ws + 8388608);
  u16* wmax_ = (u16*)(ws + 16777216);
  u16* wmin_ = (u16*)(ws + 25165824);
  float* stats = (float*)(ws + 33554432);
  float* sct   = (float*)(ws + 33554944);
  u16* wbf     = (u16*)(ws + 33555456);

  hipMemsetAsync(stats, 0, 512, stream);
  k0_wprep<<<288, 256, 0, stream>>>(wconv, wbf);
  k1_uv<<<dim3(N_/128, B_), 256, 0, stream>>>(x, we, u, v);
  k2_gather<<<4096, 256, 0, stream>>>(u, v, eidx, wmax_, wmin_, stats);
  k3_finalize<<<1, 64, 0, stream>>>(stats, gamma, beta, sct);
  k4_mfma<<<dim3(N_/64, B_), 256, 0, stream>>>(wmax_, wmin_, sct, coords, wbf, bconv, out);
}

// Round 8
// 145.749 us; speedup vs baseline: 1.4865x; 1.0112x over previous
//
#include <hip/hip_runtime.h>
#include <hip/hip_bf16.h>

#define B_ 4
#define N_ 16384
#define K_ 16
#define NEG 0.2f
#define EPSBN 1e-5f
#define INV_SIG2 2500.0f

typedef unsigned short u16;
typedef unsigned int   u32;
typedef __attribute__((ext_vector_type(8))) short short8;
typedef __attribute__((ext_vector_type(4))) float f32x4;

__device__ __forceinline__ float bf2f(u16 h){
  return __uint_as_float(((u32)h) << 16);
}
__device__ __forceinline__ u16 f2bf(float f){
  u32 x = __float_as_uint(f);
  x += 0x7fffu + ((x >> 16) & 1u);
  return (u16)(x >> 16);
}

// u/v/wmax/wmin layout: [half][B][N][32] u16 — each (batch, channel-half)
// partition is 1MB (u) + 1MB (v) -> fits one XCD's 4MB L2.

// ---------------- K0: wconv [o][c][j] fp32 -> wbf [j][o][c] bf16 ----------------
__global__ void k0_wprep(const float* __restrict__ wconv, u16* __restrict__ wbf){
  const int idx = blockIdx.x * 256 + threadIdx.x;
  if (idx < 9*128*64){
    const int j = idx >> 13;
    const int rem = idx & 8191;
    const int o = rem >> 6, c = rem & 63;
    wbf[idx] = f2bf(wconv[(o*64 + c)*9 + j]);
  }
}

// ---------------- K1: u = (W1-W2)^T x, v = W2^T x ---------------------------------
__global__ __launch_bounds__(256) void k1_uv(const float* __restrict__ x,
                                             const float* __restrict__ we,
                                             u16* __restrict__ uo,
                                             u16* __restrict__ vo){
  const int n0 = blockIdx.x * 128;
  const int b  = blockIdx.y;
  __shared__ u16   Wl[64*128];   // [c'][r] bf16, r<64 -> WA=W1-W2, r>=64 -> WB=W2
  __shared__ float Xl[64*128];   // [c'][n]
  const int tid = threadIdx.x;
  for (int idx = tid; idx < 64*128; idx += 256){
    const int cp = idx >> 7, r = idx & 127;
    float w;
    if (r < 64) w = we[r*128 + cp] - we[r*128 + 64 + cp];
    else        w = we[(r-64)*128 + 64 + cp];
    Wl[cp*128 + r] = f2bf(w);
  }
  for (int idx = tid; idx < 64*128; idx += 256){
    const int cp = idx >> 7, nl = idx & 127;
    Xl[cp*128 + nl] = x[(b*64 + cp)*N_ + n0 + nl];
  }
  __syncthreads();
  const int tr = tid & 15, tc = tid >> 4;
  float acc[8][8];
  #pragma unroll
  for (int i=0;i<8;++i)
    #pragma unroll
    for (int j=0;j<8;++j) acc[i][j] = 0.f;
  for (int cp=0; cp<64; ++cp){
    const uint4 wv = *(const uint4*)&Wl[cp*128 + tr*8];
    float wr[8];
    wr[0]=__uint_as_float(wv.x<<16); wr[1]=__uint_as_float(wv.x & 0xffff0000u);
    wr[2]=__uint_as_float(wv.y<<16); wr[3]=__uint_as_float(wv.y & 0xffff0000u);
    wr[4]=__uint_as_float(wv.z<<16); wr[5]=__uint_as_float(wv.z & 0xffff0000u);
    wr[6]=__uint_as_float(wv.w<<16); wr[7]=__uint_as_float(wv.w & 0xffff0000u);
    const float4 x0 = *(const float4*)&Xl[cp*128 + tc*8];
    const float4 x1 = *(const float4*)&Xl[cp*128 + tc*8 + 4];
    const float xr[8] = {x0.x,x0.y,x0.z,x0.w,x1.x,x1.y,x1.z,x1.w};
    #pragma unroll
    for (int i=0;i<8;++i)
      #pragma unroll
      for (int j=0;j<8;++j)
        acc[i][j] = fmaf(wr[i], xr[j], acc[i][j]);
  }
  // store: channels c = (tr&7)*8 .. +8 of u (tr<8) or v (tr>=8), split layout
  u16* arr = (tr < 8) ? uo : vo;
  const int c0 = (tr & 7) * 8;
  const int half = c0 >> 5;             // uniform per tr
  const int cb = c0 & 31;
  u16* dstb = arr + ((size_t)(half*B_ + b))*N_*32 + cb;
  #pragma unroll
  for (int ni=0; ni<8; ++ni){
    const int n = n0 + tc*8 + ni;
    u32 p0 = (u32)f2bf(acc[0][ni]) | ((u32)f2bf(acc[1][ni]) << 16);
    u32 p1 = (u32)f2bf(acc[2][ni]) | ((u32)f2bf(acc[3][ni]) << 16);
    u32 p2 = (u32)f2bf(acc[4][ni]) | ((u32)f2bf(acc[5][ni]) << 16);
    u32 p3 = (u32)f2bf(acc[6][ni]) | ((u32)f2bf(acc[7][ni]) << 16);
    *(uint4*)&dstb[(size_t)n*32] = make_uint4(p0,p1,p2,p3);
  }
}

// ---------------- K2 v8: (k-slot x channel-pair) lane mapping --------------------
// 4096 blocks x 256 thr, partition (b,half) = XCD-pinned. lane = kk*16+cg:
// kk in [0,4) = k-slot group (k = s*4+kk), cg in [0,16) = channel pair (2 ch).
// Per point: 8 independent uint gathers (one wave instr fetches 4 rows),
// idx from per-wave LDS copy (broadcast ds_read), in-lane k-reduce +
// 2 shfl_xor. ~2-4x fewer instructions per point than lane=channel.
__global__ __launch_bounds__(256) void k2_gather(const u16* __restrict__ uo,
                                                 const u16* __restrict__ vo,
                                                 const int* __restrict__ eidx,
                                                 u16* __restrict__ wmaxo,
                                                 u16* __restrict__ wmino,
                                                 float* __restrict__ stats){
  const int bid = blockIdx.x;
  const int p8  = bid & 7;
  const int b   = p8 >> 1;
  const int h   = p8 & 1;
  const int n0  = (bid >> 3) * 32;
  const int tid = threadIdx.x;
  const int wid = tid >> 6, lane = tid & 63;
  const int kk = lane >> 4, cg = lane & 15;
  const int nb = n0 + wid*8;                 // wave's 8 points
  const size_t pbase = ((size_t)(h*B_ + b))*N_*32;
  const u16* ub = uo + pbase;
  const u16* vb = vo + pbase;

  __shared__ int eL[4][2][128];              // per-wave eidx copy (4KB)
  __shared__ float redS[4][32], redQ[4][32];

  const int* e0 = eidx + (b*N_ + nb)*K_;               // j (neighbor -> v)
  const int* e1 = eidx + B_*N_*K_ + (b*N_ + nb)*K_;    // i (center   -> u)
  if (lane < 32) *(int4*)&eL[wid][0][lane*4]      = *(const int4*)(e0 + lane*4);
  else           *(int4*)&eL[wid][1][(lane-32)*4] = *(const int4*)(e1 + (lane-32)*4);
  __syncthreads();

  float s0=0.f, s1=0.f, q0=0.f, q1=0.f;

  for (int p = 0; p < 8; ++p){
    int ji[4], ii[4];
    #pragma unroll
    for (int s = 0; s < 4; ++s){
      ji[s] = eL[wid][0][p*16 + s*4 + kk];
      ii[s] = eL[wid][1][p*16 + s*4 + kk];
    }
    u32 ua[4], va[4];
    #pragma unroll
    for (int s = 0; s < 4; ++s){
      ua[s] = *(const u32*)&ub[(size_t)ii[s]*32 + cg*2];
      va[s] = *(const u32*)&vb[(size_t)ji[s]*32 + cg*2];
    }
    float hL[4], hH[4];
    #pragma unroll
    for (int s = 0; s < 4; ++s){
      hL[s] = __uint_as_float(ua[s] << 16)         + __uint_as_float(va[s] << 16);
      hH[s] = __uint_as_float(ua[s] & 0xffff0000u) + __uint_as_float(va[s] & 0xffff0000u);
    }
    float mx0 = fmaxf(fmaxf(hL[0],hL[1]), fmaxf(hL[2],hL[3]));
    float mn0 = fminf(fminf(hL[0],hL[1]), fminf(hL[2],hL[3]));
    float mx1 = fmaxf(fmaxf(hH[0],hH[1]), fmaxf(hH[2],hH[3]));
    float mn1 = fminf(fminf(hH[0],hH[1]), fminf(hH[2],hH[3]));
    s0 += (hL[0]+hL[1]) + (hL[2]+hL[3]);
    s1 += (hH[0]+hH[1]) + (hH[2]+hH[3]);
    q0 = fmaf(hL[0],hL[0], fmaf(hL[1],hL[1], fmaf(hL[2],hL[2], fmaf(hL[3],hL[3], q0))));
    q1 = fmaf(hH[0],hH[0], fmaf(hH[1],hH[1], fmaf(hH[2],hH[2], fmaf(hH[3],hH[3], q1))));
    // cross k-slot-group reduce (kk lives at lane bits 4..5)
    mx0 = fmaxf(mx0, __shfl_xor(mx0, 16)); mx0 = fmaxf(mx0, __shfl_xor(mx0, 32));
    mx1 = fmaxf(mx1, __shfl_xor(mx1, 16)); mx1 = fmaxf(mx1, __shfl_xor(mx1, 32));
    mn0 = fminf(mn0, __shfl_xor(mn0, 16)); mn0 = fminf(mn0, __shfl_xor(mn0, 32));
    mn1 = fminf(mn1, __shfl_xor(mn1, 16)); mn1 = fminf(mn1, __shfl_xor(mn1, 32));
    const int n = nb + p;
    if (lane < 16){
      const u32 pm = (u32)f2bf(mx0) | ((u32)f2bf(mx1) << 16);
      const u32 pn = (u32)f2bf(mn0) | ((u32)f2bf(mn1) << 16);
      *(u32*)&wmaxo[pbase + (size_t)n*32 + cg*2] = pm;
      *(u32*)&wmino[pbase + (size_t)n*32 + cg*2] = pn;
    }
  }

  // stats: reduce across kk groups once per wave
  s0 += __shfl_xor(s0,16); s0 += __shfl_xor(s0,32);
  s1 += __shfl_xor(s1,16); s1 += __shfl_xor(s1,32);
  q0 += __shfl_xor(q0,16); q0 += __shfl_xor(q0,32);
  q1 += __shfl_xor(q1,16); q1 += __shfl_xor(q1,32);
  if (lane < 16){
    redS[wid][cg*2]   = s0;  redS[wid][cg*2+1] = s1;
    redQ[wid][cg*2]   = q0;  redQ[wid][cg*2+1] = q1;
  }
  __syncthreads();
  if (tid < 32){
    atomicAdd(&stats[h*32 + tid], redS[0][tid]+redS[1][tid]+redS[2][tid]+redS[3][tid]);
  } else if (tid < 64){
    const int c = tid - 32;
    atomicAdd(&stats[64 + h*32 + c], redQ[0][c]+redQ[1][c]+redQ[2][c]+redQ[3][c]);
  }
}

// ---------------- K3: finalize BN affine: sct[c]=scale, sct[64+c]=shift ----------
__global__ void k3_finalize(const float* __restrict__ stats,
                            const float* __restrict__ gamma,
                            const float* __restrict__ beta,
                            float* __restrict__ sct){
  const int c = threadIdx.x;
  const float inv = 1.0f / (float)(B_*N_*K_);
  const float mean = stats[c] * inv;
  const float var  = stats[64+c] * inv - mean*mean;
  const float s = gamma[c] * rsqrtf(var + EPSBN);
  sct[c] = s;
  sct[64+c] = beta[c] - mean*s;
}

// ---------------- K4: MFMA weighted conv ------------------------------------------
// grid (N/64, B), block 256 (4 waves). Wave w: o in [w*32, w*32+32), n-tile 64.
// out[o][n] = sum_j wgt[j][n] * (Wj x hbn_shift_j)[o][n] + bias
__global__ __launch_bounds__(256) void k4_mfma(const u16* __restrict__ wmaxo,
                                               const u16* __restrict__ wmino,
                                               const float* __restrict__ sct,
                                               const float* __restrict__ coords,
                                               const u16* __restrict__ wbf,
                                               const float* __restrict__ bconv,
                                               float* __restrict__ out){
  const int n0 = blockIdx.x * 64;
  const int b  = blockIdx.y;
  const int tid = threadIdx.x;
  const int w = tid >> 6, lane = tid & 63;
  const int r15 = lane & 15, kg = lane >> 4;

  __shared__ u16 hl[72*72];     // [m_local][c], row stride 72 (pad) -> 10.4 KB
  __shared__ float wgt[9*64];   // [j][n] Gaussian weights

  // --- build hbn tile: h = leaky(s*max_or_min + t), rows m = n0-4 .. n0+67
  {
    const int c = tid & 63;
    const float s = sct[c], t = sct[64+c];
    const u16* src = ((s >= 0.f) ? wmaxo : wmino)
                   + ((size_t)((c >> 5)*B_ + b))*N_*32 + (c & 31);
    #pragma unroll
    for (int it = 0; it < 18; ++it){
      const int ml = (tid >> 6) + it*4;
      const int m = n0 - 4 + ml;
      float hv = 0.f;
      if (m >= 0 && m < N_){
        hv = fmaf(s, bf2f(src[(size_t)m*32]), t);
        hv = (hv >= 0.f) ? hv : NEG*hv;
      }
      hl[ml*72 + c] = f2bf(hv);
    }
  }
  // --- build Gaussian weights wgt[j][n]
  for (int idx = tid; idx < 576; idx += 256){
    const int j = idx >> 6, n = idx & 63;
    const int mc = n0 + n, mt = mc + j - 4;
    float wv = 0.f;
    if (mt >= 0 && mt < N_){
      float d2 = 0.f;
      #pragma unroll
      for (int d = 0; d < 3; ++d){
        const float dd = coords[(b*3+d)*N_ + mt] - coords[(b*3+d)*N_ + mc];
        d2 = fmaf(dd, dd, d2);
      }
      wv = __expf(-INV_SIG2 * d2);
    }
    wgt[idx] = wv;
  }
  __syncthreads();

  // --- MFMA main loop over taps j
  const u16* abase = wbf + ((w*32 + r15)*64 + kg*8);   // + j*8192 + of*1024 + cc
  const u16* hbase = &hl[r15*72 + kg*8];               // + (nf*16 + j)*72 + cc
  f32x4 acc[2][4] = {};
  const f32x4 zero = {0.f, 0.f, 0.f, 0.f};

  for (int j = 0; j < 9; ++j){
    float wj[4];
    #pragma unroll
    for (int nf = 0; nf < 4; ++nf) wj[nf] = wgt[j*64 + nf*16 + r15];
    short8 bfr[4][2];
    #pragma unroll
    for (int nf = 0; nf < 4; ++nf){
      bfr[nf][0] = *(const short8*)&hbase[(nf*16 + j)*72];
      bfr[nf][1] = *(const short8*)&hbase[(nf*16 + j)*72 + 32];
    }
    #pragma unroll
    for (int of = 0; of < 2; ++of){
      const short8 a0 = *(const short8*)&abase[j*8192 + of*1024];
      const short8 a1 = *(const short8*)&abase[j*8192 + of*1024 + 32];
      #pragma unroll
      for (int nf = 0; nf < 4; ++nf){
        f32x4 p = __builtin_amdgcn_mfma_f32_16x16x32_bf16(a0, bfr[nf][0], zero, 0, 0, 0);
        p = __builtin_amdgcn_mfma_f32_16x16x32_bf16(a1, bfr[nf][1], p, 0, 0, 0);
        #pragma unroll
        for (int r = 0; r < 4; ++r)
          acc[of][nf][r] = fmaf(wj[nf], p[r], acc[of][nf][r]);
      }
    }
  }

  // --- epilogue: D layout col = lane&15, row = (lane>>4)*4 + reg
  #pragma unroll
  for (int of = 0; of < 2; ++of){
    #pragma unroll
    for (int r = 0; r < 4; ++r){
      const int o = w*32 + of*16 + kg*4 + r;
      const float bs = bconv[o];
      float* dst = &out[(size_t)(b*128 + o)*N_ + n0 + r15];
      #pragma unroll
      for (int nf = 0; nf < 4; ++nf)
        dst[nf*16] = acc[of][nf][r] + bs;
    }
  }
}

extern "C" void kernel_launch(void* const* d_in, const int* in_sizes, int n_in,
                              void* d_out, int out_size, void* d_ws, size_t ws_size,
                              hipStream_t stream){
  const float* x      = (const float*)d_in[0];
  const float* coords = (const float*)d_in[1];
  const int*   eidx   = (const int*)  d_in[2];
  const float* we     = (const float*)d_in[3];
  const float* gamma  = (const float*)d_in[4];
  const float* beta   = (const float*)d_in[5];
  const float* wconv  = (const float*)d_in[6];
  const float* bconv  = (const float*)d_in[7];
  float* out = (float*)d_out;
  char* ws = (char*)d_ws;
  // ws layout (bytes): u[8.39MB] v[8.39MB] wmax[8.39MB] wmin[8.39MB] stats[512] sct[512] wbf[147KB]
  u16* u     = (u16*)(ws);
  u16* v     = (u16*)(ws + 8388608);
  u16* wmax_ = (u16*)(ws + 16777216);
  u16* wmin_ = (u16*)(ws + 25165824);
  float* stats = (float*)(ws + 33554432);
  float* sct   = (float*)(ws + 33554944);
  u16* wbf     = (u16*)(ws + 33555456);

  hipMemsetAsync(stats, 0, 512, stream);
  k0_wprep<<<288, 256, 0, stream>>>(wconv, wbf);
  k1_uv<<<dim3(N_/128, B_), 256, 0, stream>>>(x, we, u, v);
  k2_gather<<<4096, 256, 0, stream>>>(u, v, eidx, wmax_, wmin_, stats);
  k3_finalize<<<1, 64, 0, stream>>>(stats, gamma, beta, sct);
  k4_mfma<<<dim3(N_/64, B_), 256, 0, stream>>>(wmax_, wmin_, sct, coords, wbf, bconv, out);
}

// Round 9
// 125.749 us; speedup vs baseline: 1.7230x; 1.1591x over previous
//
#include <hip/hip_runtime.h>
#include <hip/hip_bf16.h>

#define B_ 4
#define N_ 16384
#define K_ 16
#define NEG 0.2f
#define EPSBN 1e-5f
#define INV_SIG2 2500.0f

typedef unsigned short u16;
typedef unsigned int   u32;
typedef __attribute__((ext_vector_type(8))) short short8;
typedef __attribute__((ext_vector_type(4))) float f32x4;

__device__ __forceinline__ float bf2f(u16 h){
  return __uint_as_float(((u32)h) << 16);
}
__device__ __forceinline__ u16 f2bf(float f){
  u32 x = __float_as_uint(f);
  x += 0x7fffu + ((x >> 16) & 1u);
  return (u16)(x >> 16);
}

// u/v/wmax/wmin layout: [half][B][N][32] u16 — each (batch, channel-half)
// partition is 1MB (u) + 1MB (v) -> fits one XCD's 4MB L2.

// ---------------- K0: wconv -> wbf [j][o][c]; we -> weA [o][c] (o<64: W1-W2, o>=64: W2)
__global__ void k0_wprep(const float* __restrict__ wconv, u16* __restrict__ wbf,
                         const float* __restrict__ we, u16* __restrict__ weA){
  const int idx = blockIdx.x * 256 + threadIdx.x;
  if (idx < 9*128*64){
    const int j = idx >> 13;
    const int rem = idx & 8191;
    const int o = rem >> 6, c = rem & 63;
    wbf[idx] = f2bf(wconv[(o*64 + c)*9 + j]);
  } else if (idx < 9*128*64 + 128*64){
    const int t = idx - 9*128*64;
    const int o = t >> 6, c = t & 63;
    float w;
    if (o < 64) w = we[o*128 + c] - we[o*128 + 64 + c];
    else        w = we[(o-64)*128 + 64 + c];
    weA[t] = f2bf(w);
  }
}

// ---------------- K1 v2: MFMA GEMM [u;v](128 x n) = weA(128x64) * x(64 x n) ------
// grid (N/64, B), 256 thr (4 waves). Wave w: output rows o in [w*32, w*32+32).
// B-fragments loaded directly from global x (L1-resident 16KB tile, coalesced);
// epilogue transposes acc through LDS for coalesced 64B row stores in the
// [half][B][N][32] layout k2 consumes.
__global__ __launch_bounds__(256) void k1_uv(const float* __restrict__ x,
                                             const u16* __restrict__ weA,
                                             u16* __restrict__ uo,
                                             u16* __restrict__ vo){
  const int n0 = blockIdx.x * 64;
  const int b  = blockIdx.y;
  const int tid = threadIdx.x;
  const int w = tid >> 6, lane = tid & 63;
  const int r15 = lane & 15, kg = lane >> 4;

  __shared__ u16 tl[128*72];   // [o][n] stride 72 -> 18.4 KB

  // A fragments: row o = w*32 + of*16 + r15, k = kg*8 (+ kh*32)
  short8 a[2][2];
  #pragma unroll
  for (int of = 0; of < 2; ++of)
    #pragma unroll
    for (int kh = 0; kh < 2; ++kh)
      a[of][kh] = *(const short8*)&weA[(w*32 + of*16 + r15)*64 + kg*8 + kh*32];

  const float* xb = x + (size_t)b*64*N_ + n0 + r15;
  f32x4 acc[2][4];
  const f32x4 zero = {0.f, 0.f, 0.f, 0.f};

  #pragma unroll
  for (int nf = 0; nf < 4; ++nf){
    short8 bq[2];
    #pragma unroll
    for (int kh = 0; kh < 2; ++kh){
      float f[8];
      #pragma unroll
      for (int e = 0; e < 8; ++e)
        f[e] = xb[(size_t)(kg*8 + kh*32 + e)*N_ + nf*16];
      union { short8 s; u32 u[4]; } bb;
      #pragma unroll
      for (int e2 = 0; e2 < 4; ++e2)
        bb.u[e2] = (u32)f2bf(f[e2*2]) | ((u32)f2bf(f[e2*2+1]) << 16);
      bq[kh] = bb.s;
    }
    #pragma unroll
    for (int of = 0; of < 2; ++of){
      f32x4 p = __builtin_amdgcn_mfma_f32_16x16x32_bf16(a[of][0], bq[0], zero, 0, 0, 0);
      acc[of][nf] = __builtin_amdgcn_mfma_f32_16x16x32_bf16(a[of][1], bq[1], p, 0, 0, 0);
    }
  }

  // transpose through LDS: D layout col = lane&15 (n), row = kg*4 + reg
  #pragma unroll
  for (int of = 0; of < 2; ++of)
    #pragma unroll
    for (int rr = 0; rr < 4; ++rr){
      const int o = w*32 + of*16 + kg*4 + rr;
      #pragma unroll
      for (int nf = 0; nf < 4; ++nf)
        tl[o*72 + nf*16 + r15] = f2bf(acc[of][nf][rr]);
    }
  __syncthreads();

  // store 256 rows (arr x half x n) of 64B each, coalesced-packed per thread
  const int arr = tid >> 7, half = (tid >> 6) & 1, n = tid & 63;
  const int ro = arr*64 + half*32;
  u32 pk[16];
  #pragma unroll
  for (int cc = 0; cc < 16; ++cc){
    const u16 lo = tl[(ro + cc*2    )*72 + n];
    const u16 hi = tl[(ro + cc*2 + 1)*72 + n];
    pk[cc] = (u32)lo | ((u32)hi << 16);
  }
  u16* dst = (arr ? vo : uo) + ((size_t)(half*B_ + b)*N_ + n0 + n)*32;
  *(uint4*)(dst +  0) = make_uint4(pk[0],  pk[1],  pk[2],  pk[3]);
  *(uint4*)(dst +  8) = make_uint4(pk[4],  pk[5],  pk[6],  pk[7]);
  *(uint4*)(dst + 16) = make_uint4(pk[8],  pk[9],  pk[10], pk[11]);
  *(uint4*)(dst + 24) = make_uint4(pk[12], pk[13], pk[14], pk[15]);
}

// ---------------- K2 v8: (k-slot x channel-pair) lane mapping (UNCHANGED) --------
__global__ __launch_bounds__(256) void k2_gather(const u16* __restrict__ uo,
                                                 const u16* __restrict__ vo,
                                                 const int* __restrict__ eidx,
                                                 u16* __restrict__ wmaxo,
                                                 u16* __restrict__ wmino,
                                                 float* __restrict__ stats){
  const int bid = blockIdx.x;
  const int p8  = bid & 7;
  const int b   = p8 >> 1;
  const int h   = p8 & 1;
  const int n0  = (bid >> 3) * 32;
  const int tid = threadIdx.x;
  const int wid = tid >> 6, lane = tid & 63;
  const int kk = lane >> 4, cg = lane & 15;
  const int nb = n0 + wid*8;                 // wave's 8 points
  const size_t pbase = ((size_t)(h*B_ + b))*N_*32;
  const u16* ub = uo + pbase;
  const u16* vb = vo + pbase;

  __shared__ int eL[4][2][128];              // per-wave eidx copy (4KB)
  __shared__ float redS[4][32], redQ[4][32];

  const int* e0 = eidx + (b*N_ + nb)*K_;               // j (neighbor -> v)
  const int* e1 = eidx + B_*N_*K_ + (b*N_ + nb)*K_;    // i (center   -> u)
  if (lane < 32) *(int4*)&eL[wid][0][lane*4]      = *(const int4*)(e0 + lane*4);
  else           *(int4*)&eL[wid][1][(lane-32)*4] = *(const int4*)(e1 + (lane-32)*4);
  __syncthreads();

  float s0=0.f, s1=0.f, q0=0.f, q1=0.f;

  for (int p = 0; p < 8; ++p){
    int ji[4], ii[4];
    #pragma unroll
    for (int s = 0; s < 4; ++s){
      ji[s] = eL[wid][0][p*16 + s*4 + kk];
      ii[s] = eL[wid][1][p*16 + s*4 + kk];
    }
    u32 ua[4], va[4];
    #pragma unroll
    for (int s = 0; s < 4; ++s){
      ua[s] = *(const u32*)&ub[(size_t)ii[s]*32 + cg*2];
      va[s] = *(const u32*)&vb[(size_t)ji[s]*32 + cg*2];
    }
    float hL[4], hH[4];
    #pragma unroll
    for (int s = 0; s < 4; ++s){
      hL[s] = __uint_as_float(ua[s] << 16)         + __uint_as_float(va[s] << 16);
      hH[s] = __uint_as_float(ua[s] & 0xffff0000u) + __uint_as_float(va[s] & 0xffff0000u);
    }
    float mx0 = fmaxf(fmaxf(hL[0],hL[1]), fmaxf(hL[2],hL[3]));
    float mn0 = fminf(fminf(hL[0],hL[1]), fminf(hL[2],hL[3]));
    float mx1 = fmaxf(fmaxf(hH[0],hH[1]), fmaxf(hH[2],hH[3]));
    float mn1 = fminf(fminf(hH[0],hH[1]), fminf(hH[2],hH[3]));
    s0 += (hL[0]+hL[1]) + (hL[2]+hL[3]);
    s1 += (hH[0]+hH[1]) + (hH[2]+hH[3]);
    q0 = fmaf(hL[0],hL[0], fmaf(hL[1],hL[1], fmaf(hL[2],hL[2], fmaf(hL[3],hL[3], q0))));
    q1 = fmaf(hH[0],hH[0], fmaf(hH[1],hH[1], fmaf(hH[2],hH[2], fmaf(hH[3],hH[3], q1))));
    mx0 = fmaxf(mx0, __shfl_xor(mx0, 16)); mx0 = fmaxf(mx0, __shfl_xor(mx0, 32));
    mx1 = fmaxf(mx1, __shfl_xor(mx1, 16)); mx1 = fmaxf(mx1, __shfl_xor(mx1, 32));
    mn0 = fminf(mn0, __shfl_xor(mn0, 16)); mn0 = fminf(mn0, __shfl_xor(mn0, 32));
    mn1 = fminf(mn1, __shfl_xor(mn1, 16)); mn1 = fminf(mn1, __shfl_xor(mn1, 32));
    const int n = nb + p;
    if (lane < 16){
      const u32 pm = (u32)f2bf(mx0) | ((u32)f2bf(mx1) << 16);
      const u32 pn = (u32)f2bf(mn0) | ((u32)f2bf(mn1) << 16);
      *(u32*)&wmaxo[pbase + (size_t)n*32 + cg*2] = pm;
      *(u32*)&wmino[pbase + (size_t)n*32 + cg*2] = pn;
    }
  }

  s0 += __shfl_xor(s0,16); s0 += __shfl_xor(s0,32);
  s1 += __shfl_xor(s1,16); s1 += __shfl_xor(s1,32);
  q0 += __shfl_xor(q0,16); q0 += __shfl_xor(q0,32);
  q1 += __shfl_xor(q1,16); q1 += __shfl_xor(q1,32);
  if (lane < 16){
    redS[wid][cg*2]   = s0;  redS[wid][cg*2+1] = s1;
    redQ[wid][cg*2]   = q0;  redQ[wid][cg*2+1] = q1;
  }
  __syncthreads();
  if (tid < 32){
    atomicAdd(&stats[h*32 + tid], redS[0][tid]+redS[1][tid]+redS[2][tid]+redS[3][tid]);
  } else if (tid < 64){
    const int c = tid - 32;
    atomicAdd(&stats[64 + h*32 + c], redQ[0][c]+redQ[1][c]+redQ[2][c]+redQ[3][c]);
  }
}

// ---------------- K4: MFMA weighted conv (k3 folded in) ---------------------------
// grid (N/64, B), block 256 (4 waves). Wave w: o in [w*32, w*32+32), n-tile 64.
__global__ __launch_bounds__(256) void k4_mfma(const u16* __restrict__ wmaxo,
                                               const u16* __restrict__ wmino,
                                               const float* __restrict__ stats,
                                               const float* __restrict__ gamma,
                                               const float* __restrict__ beta,
                                               const float* __restrict__ coords,
                                               const u16* __restrict__ wbf,
                                               const float* __restrict__ bconv,
                                               float* __restrict__ out){
  const int n0 = blockIdx.x * 64;
  const int b  = blockIdx.y;
  const int tid = threadIdx.x;
  const int w = tid >> 6, lane = tid & 63;
  const int r15 = lane & 15, kg = lane >> 4;

  __shared__ u16 hl[72*72];     // [m_local][c], row stride 72 (pad) -> 10.4 KB
  __shared__ float wgt[9*64];   // [j][n] Gaussian weights
  __shared__ float sctl[128];   // BN affine (former k3)

  if (tid < 64){
    const float inv = 1.0f / (float)(B_*N_*K_);
    const float mean = stats[tid] * inv;
    const float var  = stats[64+tid] * inv - mean*mean;
    const float s = gamma[tid] * rsqrtf(var + EPSBN);
    sctl[tid] = s;
    sctl[64+tid] = beta[tid] - mean*s;
  }
  __syncthreads();

  // --- build hbn tile: h = leaky(s*max_or_min + t), rows m = n0-4 .. n0+67
  {
    const int c = tid & 63;
    const float s = sctl[c], t = sctl[64+c];
    const u16* src = ((s >= 0.f) ? wmaxo : wmino)
                   + ((size_t)((c >> 5)*B_ + b))*N_*32 + (c & 31);
    #pragma unroll
    for (int it = 0; it < 18; ++it){
      const int ml = (tid >> 6) + it*4;
      const int m = n0 - 4 + ml;
      float hv = 0.f;
      if (m >= 0 && m < N_){
        hv = fmaf(s, bf2f(src[(size_t)m*32]), t);
        hv = (hv >= 0.f) ? hv : NEG*hv;
      }
      hl[ml*72 + c] = f2bf(hv);
    }
  }
  // --- build Gaussian weights wgt[j][n]
  for (int idx = tid; idx < 576; idx += 256){
    const int j = idx >> 6, n = idx & 63;
    const int mc = n0 + n, mt = mc + j - 4;
    float wv = 0.f;
    if (mt >= 0 && mt < N_){
      float d2 = 0.f;
      #pragma unroll
      for (int d = 0; d < 3; ++d){
        const float dd = coords[(b*3+d)*N_ + mt] - coords[(b*3+d)*N_ + mc];
        d2 = fmaf(dd, dd, d2);
      }
      wv = __expf(-INV_SIG2 * d2);
    }
    wgt[idx] = wv;
  }
  __syncthreads();

  // --- MFMA main loop over taps j
  const u16* abase = wbf + ((w*32 + r15)*64 + kg*8);   // + j*8192 + of*1024 + cc
  const u16* hbase = &hl[r15*72 + kg*8];               // + (nf*16 + j)*72 + cc
  f32x4 acc[2][4] = {};
  const f32x4 zero = {0.f, 0.f, 0.f, 0.f};

  for (int j = 0; j < 9; ++j){
    float wj[4];
    #pragma unroll
    for (int nf = 0; nf < 4; ++nf) wj[nf] = wgt[j*64 + nf*16 + r15];
    short8 bfr[4][2];
    #pragma unroll
    for (int nf = 0; nf < 4; ++nf){
      bfr[nf][0] = *(const short8*)&hbase[(nf*16 + j)*72];
      bfr[nf][1] = *(const short8*)&hbase[(nf*16 + j)*72 + 32];
    }
    #pragma unroll
    for (int of = 0; of < 2; ++of){
      const short8 a0 = *(const short8*)&abase[j*8192 + of*1024];
      const short8 a1 = *(const short8*)&abase[j*8192 + of*1024 + 32];
      #pragma unroll
      for (int nf = 0; nf < 4; ++nf){
        f32x4 p = __builtin_amdgcn_mfma_f32_16x16x32_bf16(a0, bfr[nf][0], zero, 0, 0, 0);
        p = __builtin_amdgcn_mfma_f32_16x16x32_bf16(a1, bfr[nf][1], p, 0, 0, 0);
        #pragma unroll
        for (int r = 0; r < 4; ++r)
          acc[of][nf][r] = fmaf(wj[nf], p[r], acc[of][nf][r]);
      }
    }
  }

  // --- epilogue: D layout col = lane&15, row = (lane>>4)*4 + reg
  #pragma unroll
  for (int of = 0; of < 2; ++of){
    #pragma unroll
    for (int r = 0; r < 4; ++r){
      const int o = w*32 + of*16 + kg*4 + r;
      const float bs = bconv[o];
      float* dst = &out[(size_t)(b*128 + o)*N_ + n0 + r15];
      #pragma unroll
      for (int nf = 0; nf < 4; ++nf)
        dst[nf*16] = acc[of][nf][r] + bs;
    }
  }
}

extern "C" void kernel_launch(void* const* d_in, const int* in_sizes, int n_in,
                              void* d_out, int out_size, void* d_ws, size_t ws_size,
                              hipStream_t stream){
  const float* x      = (const float*)d_in[0];
  const float* coords = (const float*)d_in[1];
  const int*   eidx   = (const int*)  d_in[2];
  const float* we     = (const float*)d_in[3];
  const float* gamma  = (const float*)d_in[4];
  const float* beta   = (const float*)d_in[5];
  const float* wconv  = (const float*)d_in[6];
  const float* bconv  = (const float*)d_in[7];
  float* out = (float*)d_out;
  char* ws = (char*)d_ws;
  // ws layout (bytes): u[8.39MB] v[8.39MB] wmax[8.39MB] wmin[8.39MB] stats[512]
  //                    (pad 512) wbf[147KB] weA[16KB]
  u16* u     = (u16*)(ws);
  u16* v     = (u16*)(ws + 8388608);
  u16* wmax_ = (u16*)(ws + 16777216);
  u16* wmin_ = (u16*)(ws + 25165824);
  float* stats = (float*)(ws + 33554432);
  u16* wbf     = (u16*)(ws + 33555456);
  u16* weA     = (u16*)(ws + 33555456 + 147456);

  hipMemsetAsync(stats, 0, 512, stream);
  k0_wprep<<<320, 256, 0, stream>>>(wconv, wbf, we, weA);
  k1_uv<<<dim3(N_/64, B_), 256, 0, stream>>>(x, weA, u, v);
  k2_gather<<<4096, 256, 0, stream>>>(u, v, eidx, wmax_, wmin_, stats);
  k4_mfma<<<dim3(N_/64, B_), 256, 0, stream>>>(wmax_, wmin_, stats, gamma, beta,
                                               coords, wbf, bconv, out);
}